// Round 14
// baseline (820.011 us; speedup 1.0000x reference)
//
#include <hip/hip_runtime.h>
#include <cmath>

namespace {

constexpr int LT = 4;       // layers
constexpr int BB = 64;      // batch
constexpr int TT = 256;     // seq len
constexpr int DD = 512;     // model dim
constexpr int HH = 8;       // heads
constexpr int DH = 64;      // head dim
constexpr int FF = 2048;    // ffn inner
constexpr int CC = 25;      // tag classes
constexpr int M_ALL = BB * TT;   // 16384 padded token rows
constexpr size_t MB = 1024 * 1024;

typedef __attribute__((ext_vector_type(8))) short short8;
typedef __attribute__((ext_vector_type(4))) short short4_;
typedef __attribute__((ext_vector_type(4))) float f32x4;
typedef __attribute__((ext_vector_type(4))) _Float16 half4;

__device__ __forceinline__ float b2f(unsigned short u) {
  union { unsigned int i; float f; } x; x.i = ((unsigned int)u) << 16; return x.f;
}
__device__ __forceinline__ unsigned short f2b(float f) {
  union { float f; unsigned int i; } x; x.f = f;
  unsigned int r = x.i + 0x7FFFu + ((x.i >> 16) & 1u);
  return (unsigned short)(r >> 16);
}
__device__ __forceinline__ float rdlane(float v, int l) {
  union { float f; unsigned int i; } x; x.f = v;
  x.i = (unsigned int)__builtin_amdgcn_readlane((int)x.i, l);
  return x.f;
}
__device__ __forceinline__ void gl_lds16(const void* g, void* l) {
  __builtin_amdgcn_global_load_lds(
      (const __attribute__((address_space(1))) unsigned int*)g,
      (__attribute__((address_space(3))) unsigned int*)l, 16, 0, 0);
}
__device__ __forceinline__ float wredsum(float v) {
#pragma unroll
  for (int o = 32; o > 0; o >>= 1) v += __shfl_xor(v, o, 64);
  return v;
}

// ---------------- token compaction: per-block prefix + rowmap (fused) -------
__global__ __launch_bounds__(256) void rowmap_k(const int* __restrict__ sl,
                                                int* __restrict__ boff,
                                                int* __restrict__ rowmap) {
  const int b = blockIdx.x;
  const int tid = threadIdx.x;
  __shared__ int sh_off;
  if (tid < 64) {
    int s = sl[tid];
#pragma unroll
    for (int o = 1; o < 64; o <<= 1) {
      const int u = __shfl_up(s, o, 64);
      if (tid >= o) s += u;
    }
    if (tid == b) sh_off = s - sl[b];        // exclusive prefix for this block
    if (b == 0) {                            // block 0 publishes boff[0..64]
      boff[tid + 1] = s;                     // boff[64] == M'
      if (tid == 0) boff[0] = 0;
    }
  }
  __syncthreads();
  const int off = sh_off;
  const int len = sl[b];
  if (tid < len) rowmap[off + tid] = (b << 8) | tid;
}

// ---------------- weight convert+transpose: [K,N] f32 -> [N,K] bf16 ---------
template <int NSRC>
__global__ __launch_bounds__(256) void wconv_k(const float* __restrict__ in0,
                                               const float* __restrict__ in1,
                                               const float* __restrict__ in2,
                                               unsigned short* __restrict__ out,
                                               int K, int N, size_t lstride,
                                               size_t sstride) {
  __shared__ float ts[64][65];
  const int k0 = blockIdx.x * 64, n0 = blockIdx.y * 64;
  const float* in = in0;
  if constexpr (NSRC == 3) {
    const int s = blockIdx.z / LT;
    in = (s == 0) ? in0 : (s == 1 ? in1 : in2);
    in += (size_t)(blockIdx.z % LT) * K * N;
    out += (size_t)(blockIdx.z % LT) * lstride + (size_t)(blockIdx.z / LT) * sstride;
  } else {
    in += (size_t)blockIdx.z * K * N;
    out += (size_t)blockIdx.z * lstride;
  }
  const int tid = threadIdx.x;
  for (int i = tid; i < 1024; i += 256) {
    const int r = i >> 4, c4 = i & 15;
    const float4 f = *(const float4*)&in[(size_t)(k0 + r) * N + n0 + c4 * 4];
    ts[r][c4 * 4 + 0] = f.x; ts[r][c4 * 4 + 1] = f.y;
    ts[r][c4 * 4 + 2] = f.z; ts[r][c4 * 4 + 3] = f.w;
  }
  __syncthreads();
  const int n_r = tid >> 2, kc = (tid & 3) * 16;
  short8 v0, v1;
#pragma unroll
  for (int j = 0; j < 8; ++j) {
    v0[j] = (short)f2b(ts[kc + j][n_r]);
    v1[j] = (short)f2b(ts[kc + 8 + j][n_r]);
  }
  unsigned short* op = out + (size_t)(n0 + n_r) * K + k0 + kc;
  *(short8*)op = v0;
  *(short8*)(op + 8) = v1;
}

// ---------------- embed + LN0 -> compacted bf16 (4 rows / block) ------------
__global__ __launch_bounds__(256) void embed_ln0_k(
    const int* __restrict__ ch, const int* __restrict__ wd, const int* __restrict__ ps,
    const float* __restrict__ spo, const float* __restrict__ ctab,
    const float* __restrict__ wtab, const float* __restrict__ ptab,
    const float* __restrict__ g, const float* __restrict__ be,
    const int* __restrict__ sl, const int* __restrict__ boff,
    unsigned short* __restrict__ xc) {
  const int row = blockIdx.x * 4 + (threadIdx.x >> 6);
  const int b = row >> 8, t = row & 255;
  if (t >= sl[b]) return;            // dead token (per-wave uniform exit)
  const int orow = boff[b] + t;
  const int lane = threadIdx.x & 63;
  const int ci = ch[row], wi = wd[row], pi = ps[row];
  float v[8];
#pragma unroll
  for (int j = 0; j < 2; ++j) {
    const int d = j * 256 + lane * 4;
    float4 f;
    if (d < 128)      f = *(const float4*)&ctab[(size_t)ci * 128 + d];
    else if (d < 428) f = *(const float4*)&wtab[(size_t)wi * 300 + (d - 128)];
    else if (d < 492) f = *(const float4*)&ptab[(size_t)pi * 64 + (d - 428)];
    else              f = *(const float4*)&spo[(size_t)b * 20 + (d - 492)];
    v[j * 4 + 0] = f.x; v[j * 4 + 1] = f.y; v[j * 4 + 2] = f.z; v[j * 4 + 3] = f.w;
  }
  float s = 0.f;
#pragma unroll
  for (int i = 0; i < 8; ++i) s += v[i];
  const float mean = wredsum(s) * (1.0f / 512.0f);
  float vs = 0.f;
#pragma unroll
  for (int i = 0; i < 8; ++i) { const float d = v[i] - mean; vs += d * d; }
  const float rstd = rsqrtf(wredsum(vs) * (1.0f / 512.0f) + 1e-5f);
#pragma unroll
  for (int j = 0; j < 2; ++j) {
    const int d = j * 256 + lane * 4;
    const float4 gv = *(const float4*)&g[d];
    const float4 bv = *(const float4*)&be[d];
    short4_ ob;
    ob[0] = (short)f2b((v[j * 4 + 0] - mean) * rstd * gv.x + bv.x);
    ob[1] = (short)f2b((v[j * 4 + 1] - mean) * rstd * gv.y + bv.y);
    ob[2] = (short)f2b((v[j * 4 + 2] - mean) * rstd * gv.z + bv.z);
    ob[3] = (short)f2b((v[j * 4 + 3] - mean) * rstd * gv.w + bv.w);
    *(short4_*)&xc[(size_t)orow * DD + d] = ob;
  }
}

// ---------------- MFMA GEMM, TMxTN tile, 2-buffer issue-ahead ---------------
// TM=TN=64: LDS 32KB -> 5 blocks/CU, 2x live blocks vs TN=128. Cross-block
// overlap is the latency-hiding mechanism on this structure (R12/R13 wins).
// Live-aware swizzle: XCD d%8 owns m-panels == d%8 (mod 8), walks all n of
// one panel -> A-panel stays L2-resident. Bijective (nwg%8==0).
// EPI: 1 bf16+bias+relu; 5 fused QKV scatter via rowmap; 7 bf16+bias+bf16 res
template <int EPI, int TM, int TN>
__global__ __launch_bounds__(256) void gemm_mfma(
    const unsigned short* __restrict__ A, const unsigned short* __restrict__ Bt,
    const float* __restrict__ bias, const float* __restrict__ bias2,
    const float* __restrict__ bias3, const unsigned short* __restrict__ res,
    const int* __restrict__ Mptr, const int* __restrict__ rowmap,
    void* __restrict__ outv, void* __restrict__ out2v, void* __restrict__ out3v,
    int M, int N, int K) {
  constexpr int MI = TM / 32;          // m-frags per wave
  constexpr int NI = TN / 32;          // n-frags per wave
  const int Mp = Mptr[0];
  const int nx = gridDim.x;
  const int flat = blockIdx.y * nx + blockIdx.x;
  const int mlo = flat & 7, rr_ = flat >> 3;
  const int bx = rr_ % nx, by = (rr_ / nx) * 8 + mlo;
  const int m0 = by * TM, n0 = bx * TN;
  if (m0 >= Mp) return;  // block-uniform exit (whole tile dead)
  __shared__ unsigned short As[2][TM * 64];
  __shared__ unsigned short Bs[2][TN * 64];
  const int tid = threadIdx.x;
  const int wid = tid >> 6, lane = tid & 63;
  const int wr = wid >> 1, wc = wid & 1;
  const int cl = lane & 15, rg = lane >> 4;
  f32x4 acc[MI][NI];
#pragma unroll
  for (int i = 0; i < MI; ++i)
#pragma unroll
    for (int j = 0; j < NI; ++j) acc[i][j] = (f32x4){0.f, 0.f, 0.f, 0.f};

  const int rbase = tid >> 3, sl = tid & 7;
  const int sc = 8 * (sl ^ (rbase & 7));  // pre-swizzled source column (elems)

  auto stage = [&](int buf, int k0) {
#pragma unroll
    for (int i = 0; i < TM / 32; ++i) {
      const int r = i * 32 + rbase;
      gl_lds16(A + (size_t)(m0 + r) * K + k0 + sc,
               (char*)As[buf] + (i * 256 + tid) * 16);
    }
#pragma unroll
    for (int i = 0; i < TN / 32; ++i) {
      const int r = i * 32 + rbase;
      gl_lds16(Bt + (size_t)(n0 + r) * K + k0 + sc,
               (char*)Bs[buf] + (i * 256 + tid) * 16);
    }
  };

  stage(0, 0);
  __syncthreads();  // implicit vmcnt(0) drain: buf0 staged
  int cur = 0;
  for (int k0 = 0; k0 < K; k0 += 64) {
    if (k0 + 64 < K) stage(cur ^ 1, k0 + 64);  // issue-ahead: latency under MFMA
#pragma unroll
    for (int ks = 0; ks < 2; ++ks) {
      short8 a[MI], b[NI];
      const int kbyte = ks * 64 + rg * 16;
#pragma unroll
      for (int f = 0; f < MI; ++f) {
        const int am = wr * (TM / 2) + f * 16 + cl;
        a[f] = *(const short8*)((const char*)As[cur] + am * 128 +
                                (kbyte ^ ((am & 7) << 4)));
      }
#pragma unroll
      for (int f = 0; f < NI; ++f) {
        const int bn = wc * (TN / 2) + f * 16 + cl;
        b[f] = *(const short8*)((const char*)Bs[cur] + bn * 128 +
                                (kbyte ^ ((bn & 7) << 4)));
      }
#pragma unroll
      for (int mi = 0; mi < MI; ++mi)
#pragma unroll
        for (int ni = 0; ni < NI; ++ni)
          acc[mi][ni] = __builtin_amdgcn_mfma_f32_16x16x32_bf16(a[mi], b[ni],
                                                                acc[mi][ni], 0, 0, 0);
    }
    __syncthreads();  // drains this iter's stage; frees buf[cur]
    cur ^= 1;
  }

  int rm[MI][4];
  if constexpr (EPI == 5) {
#pragma unroll
    for (int mi = 0; mi < MI; ++mi) {
      const int mb_ = m0 + wr * (TM / 2) + mi * 16 + rg * 4;
#pragma unroll
      for (int i = 0; i < 4; ++i)
        rm[mi][i] = (mb_ + i < Mp) ? rowmap[mb_ + i] : -1;
    }
  }

#pragma unroll
  for (int ni = 0; ni < NI; ++ni) {
    const int n = n0 + wc * (TN / 2) + ni * 16 + cl;
    float bv;
    if constexpr (EPI == 5) {
      bv = (n < 512) ? bias[n] : (n < 1024 ? bias2[n - 512] : bias3[n - 1024]);
    } else {
      bv = bias[n];
    }
#pragma unroll
    for (int mi = 0; mi < MI; ++mi) {
      if constexpr (EPI == 5) {
        const int hh = (n >> 6) & 7, d = n & 63;
        if (n < 1024) {        // q or k scatter [B,H,T,DH] bf16
          unsigned short* outp = (unsigned short*)((n < 512) ? outv : out2v);
#pragma unroll
          for (int i = 0; i < 4; ++i) {
            const int rmv = rm[mi][i];
            if (rmv >= 0) {
              const int bb = rmv >> 8, tt = rmv & 255;
              outp[(((size_t)(bb * HH + hh) * TT + tt) << 6) + d] =
                  f2b(acc[mi][ni][i] + bv);
            }
          }
        } else {               // v scatter [B,H,DH,T] f16
          const int rm0 = rm[mi][0];
          if (rm0 >= 0 && rm[mi][3] == rm0 + 3) {   // contiguous, same b
            half4 pk;
#pragma unroll
            for (int i = 0; i < 4; ++i) pk[i] = (_Float16)(acc[mi][ni][i] + bv);
            *(half4*)((_Float16*)out3v +
                      ((((size_t)((rm0 >> 8) * HH + hh) * DH + d) << 8) + (rm0 & 255))) = pk;
          } else {
#pragma unroll
            for (int i = 0; i < 4; ++i) {
              const int rmv = rm[mi][i];
              if (rmv >= 0)
                ((_Float16*)out3v)[(((size_t)((rmv >> 8) * HH + hh) * DH + d) << 8) +
                                   (rmv & 255)] = (_Float16)(acc[mi][ni][i] + bv);
            }
          }
        }
      } else {
#pragma unroll
        for (int i = 0; i < 4; ++i) {
          const int m = m0 + wr * (TM / 2) + mi * 16 + rg * 4 + i;
          const float v = acc[mi][ni][i] + bv;
          if constexpr (EPI == 1) {
            ((unsigned short*)outv)[(size_t)m * N + n] = f2b(fmaxf(v, 0.f));
          } else if constexpr (EPI == 7) {
            ((unsigned short*)outv)[(size_t)m * N + n] =
                f2b(v + b2f(res[(size_t)m * N + n]));
          }
        }
      }
    }
  }
}

// ---------------- MFMA flash attention, one block per (b,h,q-tile) ----------
__global__ __launch_bounds__(256) void attn_mfma_k(
    const unsigned short* __restrict__ qb, const unsigned short* __restrict__ kbp,
    const _Float16* __restrict__ vtp, const int* __restrict__ seq_len,
    const int* __restrict__ boff, unsigned short* __restrict__ cb) {
  __shared__ unsigned short Ks[256 * 64];  // [t][d] bf16, 16B-slot XOR swizzle
  __shared__ _Float16 Vs[64 * 256];        // [d][t] f16, swizzled
  __shared__ unsigned short Os[64 * 64];   // out transpose stage, swizzled
  const int bh = blockIdx.x >> 2;
  const int qt4 = blockIdx.x & 3;
  const int b = bh >> 3, h = bh & 7;
  const int len = seq_len[b];
  if (qt4 * 64 >= len) return;  // block-uniform early exit
  const int tid = threadIdx.x;
  const int wid = tid >> 6, lane = tid & 63;
  const int cl = lane & 15, rg = lane >> 4;
  const int off = boff[b];

  {  // stage K (len-bounded) and V^T (skip dead 64-col groups)
    const int r = tid >> 3, sl = tid & 7;
#pragma unroll
    for (int i = 0; i < 8; ++i) {
      if (i * 32 < len) {
        const int row = i * 32 + r;
        gl_lds16(kbp + ((size_t)bh * TT + row) * DH + 8 * (sl ^ (row & 7)),
                 (char*)Ks + (i * 256 + tid) * 16);
      }
    }
#pragma unroll
    for (int i = 0; i < 8; ++i) {
      const int u = i * 256 + tid;
      const int vrow = u >> 5, vsl = u & 31;
      if (64 * (vsl >> 3) < len)
        gl_lds16(vtp + ((size_t)bh * DH + vrow) * TT + 8 * (vsl ^ (vrow & 7)),
                 (char*)Vs + u * 16);
    }
  }
  __syncthreads();

  f32x4 o[4];
#pragma unroll
  for (int db = 0; db < 4; ++db) o[db] = (f32x4){0.f, 0.f, 0.f, 0.f};
  {
    const int q0 = qt4 * 64 + wid * 16;
    short8 bqf[2];
    const unsigned short* qp = qb + ((size_t)bh * TT + q0 + cl) * DH + rg * 8;
    bqf[0] = *(const short8*)qp;
    bqf[1] = *(const short8*)(qp + 32);
    f32x4 s[16];
#pragma unroll
    for (int kk = 0; kk < 16; ++kk) {
      s[kk] = (f32x4){0.f, 0.f, 0.f, 0.f};
      if (kk * 16 < len) {
        const int row = kk * 16 + cl;
        const char* base = (const char*)Ks + row * 128;
        const int sw = (row & 7) << 4;
        const short8 a0 = *(const short8*)(base + ((rg * 16) ^ sw));
        const short8 a1 = *(const short8*)(base + ((64 + rg * 16) ^ sw));
        s[kk] = __builtin_amdgcn_mfma_f32_16x16x32_bf16(a0, bqf[0], s[kk], 0, 0, 0);
        s[kk] = __builtin_amdgcn_mfma_f32_16x16x32_bf16(a1, bqf[1], s[kk], 0, 0, 0);
      }
    }
    float mx = -3.0e38f;
#pragma unroll
    for (int kk = 0; kk < 16; ++kk)
      if (kk * 16 < len) {
#pragma unroll
        for (int i = 0; i < 4; ++i) {
          float v = s[kk][i] * 0.125f;
          v = (kk * 16 + rg * 4 + i < len) ? v : -3.0e38f;
          s[kk][i] = v;
          mx = fmaxf(mx, v);
        }
      }
    mx = fmaxf(mx, __shfl_xor(mx, 16, 64));
    mx = fmaxf(mx, __shfl_xor(mx, 32, 64));
    float lsum = 0.f;
#pragma unroll
    for (int kk = 0; kk < 16; ++kk)
      if (kk * 16 < len) {
#pragma unroll
        for (int i = 0; i < 4; ++i) {
          const float p = __expf(s[kk][i] - mx);
          s[kk][i] = p;
          lsum += p;
        }
      }
    lsum += __shfl_xor(lsum, 16, 64);
    lsum += __shfl_xor(lsum, 32, 64);
    const float rl = 1.0f / lsum;
#pragma unroll
    for (int kk = 0; kk < 16; ++kk)
      if (kk * 16 < len) {
        half4 bp;
#pragma unroll
        for (int i = 0; i < 4; ++i) bp[i] = (_Float16)(s[kk][i] * rl);
#pragma unroll
        for (int db = 0; db < 4; ++db) {
          const int vrow = db * 16 + cl;
          const int byte = kk * 32 + rg * 8;
          const half4 a = *(const half4*)((const char*)Vs + vrow * 512 +
                            ((byte & ~15) ^ ((vrow & 7) << 4)) + (byte & 15));
          o[db] = __builtin_amdgcn_mfma_f32_16x16x16f16(a, bp, o[db], 0, 0, 0);
        }
      }
  }
  {  // write ctx^T frags into Os (no barrier needed: Os untouched so far)
    const int orow = wid * 16 + cl;
    char* obase = (char*)Os + orow * 128;
    const int sw = (orow & 7) << 4;
#pragma unroll
    for (int db = 0; db < 4; ++db) {
      short4_ pk;
#pragma unroll
      for (int i = 0; i < 4; ++i) pk[i] = (short)f2b(o[db][i]);
      const int byte = db * 32 + rg * 8;
      *(short4_*)(obase + ((byte & ~15) ^ sw) + (byte & 15)) = pk;
    }
  }
  __syncthreads();
  {  // coalesced copy Os (64q x 64d bf16) -> compacted cb, rows t < len only
    const int r = tid >> 2, part = tid & 3;
    const int t = qt4 * 64 + r;
    if (t < len) {
      const int sw = (r & 7) << 4;
      const char* rbase = (const char*)Os + r * 128;
      const short8 w0 = *(const short8*)(rbase + ((part * 32) ^ sw));
      const short8 w1 = *(const short8*)(rbase + ((part * 32 + 16) ^ sw));
      unsigned short* dst = cb + ((size_t)(off + t)) * DD + h * DH + part * 16;
      *(short8*)dst = w0;
      *(short8*)(dst + 8) = w1;
    }
  }
}

// ---------------- row LayerNorm (compacted, 4 rows / block) -----------------
__global__ __launch_bounds__(256) void ln_k(const unsigned short* __restrict__ a,
                                            const float* __restrict__ g,
                                            const float* __restrict__ be,
                                            const int* __restrict__ Mptr,
                                            unsigned short* __restrict__ outb) {
  const int row = blockIdx.x * 4 + (threadIdx.x >> 6);
  if (row >= Mptr[0]) return;  // per-wave uniform exit (no barriers below)
  const int lane = threadIdx.x & 63;
  float v[8];
  {
    const short8 va = *(const short8*)&a[(size_t)row * DD + lane * 8];
#pragma unroll
    for (int i = 0; i < 8; ++i) v[i] = b2f((unsigned short)va[i]);
  }
  float s = 0.f;
#pragma unroll
  for (int i = 0; i < 8; ++i) s += v[i];
  const float mean = wredsum(s) * (1.0f / 512.0f);
  float vs = 0.f;
#pragma unroll
  for (int i = 0; i < 8; ++i) { const float d = v[i] - mean; vs += d * d; }
  const float rstd = rsqrtf(wredsum(vs) * (1.0f / 512.0f) + 1e-5f);
  const float4 g0 = *(const float4*)&g[lane * 8];
  const float4 g1 = *(const float4*)&g[lane * 8 + 4];
  const float4 b0 = *(const float4*)&be[lane * 8];
  const float4 b1 = *(const float4*)&be[lane * 8 + 4];
  const float gg[8] = {g0.x, g0.y, g0.z, g0.w, g1.x, g1.y, g1.z, g1.w};
  const float bb[8] = {b0.x, b0.y, b0.z, b0.w, b1.x, b1.y, b1.z, b1.w};
  short8 ob;
#pragma unroll
  for (int i = 0; i < 8; ++i)
    ob[i] = (short)f2b((v[i] - mean) * rstd * gg[i] + bb[i]);
  *(short8*)&outb[(size_t)row * DD + lane * 8] = ob;
}

// ---------------- logits = xc(bf16) @ Wout + bout,  N=25 --------------------
__global__ __launch_bounds__(256) void logits_k(const unsigned short* __restrict__ xb,
                                                const float* __restrict__ W,
                                                const float* __restrict__ bo,
                                                const int* __restrict__ Mptr,
                                                float* __restrict__ lg) {
  const int r0 = blockIdx.x * 8;
  if (r0 >= Mptr[0]) return;
  __shared__ float xs[8][516];
  for (int i = threadIdx.x; i < 512; i += 256) {
    const int rr = i >> 6, c8 = (i & 63) * 8;
    const short8 v = *(const short8*)&xb[(size_t)(r0 + rr) * DD + c8];
#pragma unroll
    for (int j = 0; j < 8; ++j) xs[rr][c8 + j] = b2f((unsigned short)v[j]);
  }
  __syncthreads();
  const int r = threadIdx.x >> 5, c = threadIdx.x & 31;
  if (c < CC) {
    float acc = 0.f;
#pragma unroll 8
    for (int k = 0; k < DD; ++k) acc += xs[r][k] * W[k * CC + c];
    lg[(size_t)(r0 + r) * CC + c] = acc + bo[c];
  }
}

// ---------------- CRF: linear-domain scan via v_readlane (compacted) --------
__global__ __launch_bounds__(64) void crf_k(const float* __restrict__ lg,
                                            const int* __restrict__ tag,
                                            const int* __restrict__ seq_len,
                                            const int* __restrict__ boff,
                                            const float* __restrict__ trans,
                                            float* __restrict__ nll) {
  __shared__ float eexp[TT * CC + 64];
  __shared__ float tr[CC * CC];
  const int b = blockIdx.x;
  const int l = threadIdx.x;
  const int len = seq_len[b];
  const float* lgb = lg + (size_t)boff[b] * CC;
  for (int i = l; i < len * CC; i += 64) eexp[i] = __expf(lgb[i]);
  for (int i = l; i < CC * CC; i += 64) tr[i] = trans[i];
  __syncthreads();
  const int lc = (l < CC) ? l : (CC - 1);
  float et[CC];
#pragma unroll
  for (int i = 0; i < CC; ++i) et[i] = __expf(tr[i * CC + lc]);
  const float e00 = lgb[0];
  float M = e00;
  float A = (l < CC) ? __expf(lgb[l] - e00) : 0.f;
  for (int t = 1; t < len; ++t) {
    const float e = eexp[t * CC + lc];
    float s0 = 0.f, s1 = 0.f, s2 = 0.f, s3 = 0.f, s4 = 0.f;
#pragma unroll
    for (int i = 0; i < CC; i += 5) {
      s0 += rdlane(A, i + 0) * et[i + 0];
      s1 += rdlane(A, i + 1) * et[i + 1];
      s2 += rdlane(A, i + 2) * et[i + 2];
      s3 += rdlane(A, i + 3) * et[i + 3];
      s4 += rdlane(A, i + 4) * et[i + 4];
    }
    A = (((s0 + s1) + (s2 + s3)) + s4) * e;
    if ((t & 3) == 0) {
      const float r = rdlane(A, 0);  // A_0 > 0 always (dense transitions)
      M += __logf(r);
      A *= __builtin_amdgcn_rcpf(r);
    }
  }
  const float tot = wredsum((l < CC) ? A : 0.f);
  float gold = 0.f;
  for (int t = l; t < len; t += 64)
    gold += lgb[t * CC + tag[b * TT + t]];
  for (int t = 1 + l; t < len; t += 64)
    gold += tr[tag[b * TT + t - 1] * CC + tag[b * TT + t]];
  gold = wredsum(gold);
  if (l == 0) nll[b] = (M + __logf(tot)) - gold;
}

__global__ __launch_bounds__(64) void final_k(const float* __restrict__ nll,
                                              float* __restrict__ out) {
  float v = nll[threadIdx.x];
  v = wredsum(v);
  if (threadIdx.x == 0) out[0] = v * (1.0f / 64.0f);
}

}  // namespace

extern "C" void kernel_launch(void* const* d_in, const int* in_sizes, int n_in,
                              void* d_out, int out_size, void* d_ws, size_t ws_size,
                              hipStream_t stream) {
  (void)in_sizes; (void)n_in; (void)out_size; (void)ws_size;
  const int* chi = (const int*)d_in[0];
  const int* wdi = (const int*)d_in[1];
  const int* psi = (const int*)d_in[2];
  const float* spo = (const float*)d_in[3];
  const int* seq_len = (const int*)d_in[4];
  const int* tag = (const int*)d_in[5];
  const float* ctab = (const float*)d_in[6];
  const float* wtab = (const float*)d_in[7];
  const float* ptab = (const float*)d_in[8];
  const float* ln0g = (const float*)d_in[9];
  const float* ln0b = (const float*)d_in[10];
  const float* Wq = (const float*)d_in[11];
  const float* bq = (const float*)d_in[12];
  const float* Wk = (const float*)d_in[13];
  const float* bk = (const float*)d_in[14];
  const float* Wv = (const float*)d_in[15];
  const float* bv = (const float*)d_in[16];
  const float* Wo = (const float*)d_in[17];
  const float* bo = (const float*)d_in[18];
  const float* ln1g = (const float*)d_in[19];
  const float* ln1b = (const float*)d_in[20];
  const float* W1 = (const float*)d_in[21];
  const float* b1 = (const float*)d_in[22];
  const float* W2 = (const float*)d_in[23];
  const float* b2 = (const float*)d_in[24];
  const float* ln2g = (const float*)d_in[25];
  const float* ln2b = (const float*)d_in[26];
  const float* Wout = (const float*)d_in[27];
  const float* bout = (const float*)d_in[28];
  const float* trans = (const float*)d_in[29];

  // ---- workspace layout (~221 MB), all buffers disjoint ----
  char* w8 = (char*)d_ws;
  unsigned short* ib  = (unsigned short*)(w8);             // 64MB ffn inner [16384][2048]
  unsigned short* xc  = (unsigned short*)(w8 + 64 * MB);   // 16MB x compact bf16
  unsigned short* cbx = (unsigned short*)(w8 + 80 * MB);   // 16MB ctx compact bf16
  unsigned short* ab  = (unsigned short*)(w8 + 96 * MB);   // 16MB att_out+x bf16
  unsigned short* hb  = (unsigned short*)(w8 + 112 * MB);  // 16MB h1 bf16
  unsigned short* t0b = (unsigned short*)(w8 + 128 * MB);  // 16MB ffn_out+h1 bf16
  unsigned short* qbuf = (unsigned short*)(w8 + 144 * MB); // 16MB q bf16 [B,H,T,DH]
  unsigned short* kbuf = (unsigned short*)(w8 + 160 * MB); // 16MB k bf16 [B,H,T,DH]
  _Float16* vtb = (_Float16*)(w8 + 176 * MB);              // 16MB v^T f16 [B,H,DH,T]
  unsigned short* wqkv = (unsigned short*)(w8 + 192 * MB); // [L][1536][512] 6MB
  unsigned short* wot = (unsigned short*)(w8 + 198 * MB);  // [L][512][512] 2MB
  unsigned short* w1t = (unsigned short*)(w8 + 200 * MB);  // [L][2048][512] 8MB
  unsigned short* w2t = (unsigned short*)(w8 + 208 * MB);  // [L][512][2048] 8MB
  float* lg = (float*)(w8 + 216 * MB);                     // 16384*25 f32
  float* nll = (float*)(w8 + 218 * MB);
  int* boff = (int*)(w8 + 219 * MB);                       // [65]; boff[64] = M'
  int* rowmap = (int*)(w8 + 220 * MB);                     // [16384] (b<<8)|t
  const int* Mptr = boff + 64;

  rowmap_k<<<BB, 256, 0, stream>>>(seq_len, boff, rowmap);

  const size_t QKVS = (size_t)1536 * 512;
  wconv_k<3><<<dim3(8, 8, 3 * LT), 256, 0, stream>>>(
      Wq, Wk, Wv, wqkv, DD, DD, QKVS, (size_t)512 * 512);
  wconv_k<1><<<dim3(8, 8, LT), 256, 0, stream>>>(
      Wo, nullptr, nullptr, wot, DD, DD, (size_t)DD * DD, 0);
  wconv_k<1><<<dim3(8, 32, LT), 256, 0, stream>>>(
      W1, nullptr, nullptr, w1t, DD, FF, (size_t)DD * FF, 0);
  wconv_k<1><<<dim3(32, 8, LT), 256, 0, stream>>>(
      W2, nullptr, nullptr, w2t, FF, DD, (size_t)FF * DD, 0);

  embed_ln0_k<<<M_ALL / 4, 256, 0, stream>>>(chi, wdi, psi, spo, ctab, wtab, ptab,
                                             ln0g, ln0b, seq_len, boff, xc);

  for (int l = 0; l < LT; ++l) {
    gemm_mfma<5, 64, 64><<<dim3(24, 256), 256, 0, stream>>>(
        xc, wqkv + (size_t)l * QKVS, bq + l * DD, bk + l * DD, bv + l * DD,
        nullptr, Mptr, rowmap, qbuf, kbuf, vtb, M_ALL, 1536, DD);
    attn_mfma_k<<<BB * HH * 4, 256, 0, stream>>>(qbuf, kbuf, vtb, seq_len, boff, cbx);
    gemm_mfma<7, 64, 64><<<dim3(8, 256), 256, 0, stream>>>(
        cbx, wot + (size_t)l * DD * DD, bo + l * DD, nullptr, nullptr,
        xc, Mptr, nullptr, ab, nullptr, nullptr, M_ALL, DD, DD);
    ln_k<<<M_ALL / 4, 256, 0, stream>>>(ab, ln1g + l * DD, ln1b + l * DD, Mptr, hb);
    gemm_mfma<1, 64, 64><<<dim3(FF / 64, 256), 256, 0, stream>>>(
        hb, w1t + (size_t)l * FF * DD, b1 + l * FF, nullptr, nullptr,
        nullptr, Mptr, nullptr, ib, nullptr, nullptr, M_ALL, FF, DD);
    gemm_mfma<7, 64, 64><<<dim3(8, 256), 256, 0, stream>>>(
        ib, w2t + (size_t)l * FF * DD, b2 + l * DD, nullptr, nullptr,
        hb, Mptr, nullptr, t0b, nullptr, nullptr, M_ALL, DD, FF);
    ln_k<<<M_ALL / 4, 256, 0, stream>>>(t0b, ln2g + l * DD, ln2b + l * DD, Mptr, xc);
  }
  logits_k<<<M_ALL / 8, 256, 0, stream>>>(xc, Wout, bout, Mptr, lg);
  crf_k<<<BB, 64, 0, stream>>>(lg, tag, seq_len, boff, trans, nll);
  final_k<<<1, 64, 0, stream>>>(nll, (float*)d_out);
}

// Round 15
// 737.175 us; speedup vs baseline: 1.1124x; 1.1124x over previous
//
#include <hip/hip_runtime.h>
#include <cmath>

namespace {

constexpr int LT = 4;       // layers
constexpr int BB = 64;      // batch
constexpr int TT = 256;     // seq len
constexpr int DD = 512;     // model dim
constexpr int HH = 8;       // heads
constexpr int DH = 64;      // head dim
constexpr int FF = 2048;    // ffn inner
constexpr int CC = 25;      // tag classes
constexpr int M_ALL = BB * TT;   // 16384 padded token rows
constexpr size_t MB = 1024 * 1024;

typedef __attribute__((ext_vector_type(8))) short short8;
typedef __attribute__((ext_vector_type(4))) short short4_;
typedef __attribute__((ext_vector_type(4))) float f32x4;
typedef __attribute__((ext_vector_type(4))) _Float16 half4;

__device__ __forceinline__ float b2f(unsigned short u) {
  union { unsigned int i; float f; } x; x.i = ((unsigned int)u) << 16; return x.f;
}
__device__ __forceinline__ unsigned short f2b(float f) {
  union { float f; unsigned int i; } x; x.f = f;
  unsigned int r = x.i + 0x7FFFu + ((x.i >> 16) & 1u);
  return (unsigned short)(r >> 16);
}
__device__ __forceinline__ float rdlane(float v, int l) {
  union { float f; unsigned int i; } x; x.f = v;
  x.i = (unsigned int)__builtin_amdgcn_readlane((int)x.i, l);
  return x.f;
}
__device__ __forceinline__ void gl_lds16(const void* g, void* l) {
  __builtin_amdgcn_global_load_lds(
      (const __attribute__((address_space(1))) unsigned int*)g,
      (__attribute__((address_space(3))) unsigned int*)l, 16, 0, 0);
}
__device__ __forceinline__ float wredsum(float v) {
#pragma unroll
  for (int o = 32; o > 0; o >>= 1) v += __shfl_xor(v, o, 64);
  return v;
}

// ---------------- token compaction: per-block prefix + rowmap (fused) -------
__global__ __launch_bounds__(256) void rowmap_k(const int* __restrict__ sl,
                                                int* __restrict__ boff,
                                                int* __restrict__ rowmap) {
  const int b = blockIdx.x;
  const int tid = threadIdx.x;
  __shared__ int sh_off;
  if (tid < 64) {
    int s = sl[tid];
#pragma unroll
    for (int o = 1; o < 64; o <<= 1) {
      const int u = __shfl_up(s, o, 64);
      if (tid >= o) s += u;
    }
    if (tid == b) sh_off = s - sl[b];        // exclusive prefix for this block
    if (b == 0) {                            // block 0 publishes boff[0..64]
      boff[tid + 1] = s;                     // boff[64] == M'
      if (tid == 0) boff[0] = 0;
    }
  }
  __syncthreads();
  const int off = sh_off;
  const int len = sl[b];
  if (tid < len) rowmap[off + tid] = (b << 8) | tid;
}

// ---------------- weight convert+transpose: [K,N] f32 -> [N,K] bf16 ---------
template <int NSRC>
__global__ __launch_bounds__(256) void wconv_k(const float* __restrict__ in0,
                                               const float* __restrict__ in1,
                                               const float* __restrict__ in2,
                                               unsigned short* __restrict__ out,
                                               int K, int N, size_t lstride,
                                               size_t sstride) {
  __shared__ float ts[64][65];
  const int k0 = blockIdx.x * 64, n0 = blockIdx.y * 64;
  const float* in = in0;
  if constexpr (NSRC == 3) {
    const int s = blockIdx.z / LT;
    in = (s == 0) ? in0 : (s == 1 ? in1 : in2);
    in += (size_t)(blockIdx.z % LT) * K * N;
    out += (size_t)(blockIdx.z % LT) * lstride + (size_t)(blockIdx.z / LT) * sstride;
  } else {
    in += (size_t)blockIdx.z * K * N;
    out += (size_t)blockIdx.z * lstride;
  }
  const int tid = threadIdx.x;
  for (int i = tid; i < 1024; i += 256) {
    const int r = i >> 4, c4 = i & 15;
    const float4 f = *(const float4*)&in[(size_t)(k0 + r) * N + n0 + c4 * 4];
    ts[r][c4 * 4 + 0] = f.x; ts[r][c4 * 4 + 1] = f.y;
    ts[r][c4 * 4 + 2] = f.z; ts[r][c4 * 4 + 3] = f.w;
  }
  __syncthreads();
  const int n_r = tid >> 2, kc = (tid & 3) * 16;
  short8 v0, v1;
#pragma unroll
  for (int j = 0; j < 8; ++j) {
    v0[j] = (short)f2b(ts[kc + j][n_r]);
    v1[j] = (short)f2b(ts[kc + 8 + j][n_r]);
  }
  unsigned short* op = out + (size_t)(n0 + n_r) * K + k0 + kc;
  *(short8*)op = v0;
  *(short8*)(op + 8) = v1;
}

// ---------------- embed + LN0 -> compacted bf16 (4 rows / block) ------------
__global__ __launch_bounds__(256) void embed_ln0_k(
    const int* __restrict__ ch, const int* __restrict__ wd, const int* __restrict__ ps,
    const float* __restrict__ spo, const float* __restrict__ ctab,
    const float* __restrict__ wtab, const float* __restrict__ ptab,
    const float* __restrict__ g, const float* __restrict__ be,
    const int* __restrict__ sl, const int* __restrict__ boff,
    unsigned short* __restrict__ xc) {
  const int row = blockIdx.x * 4 + (threadIdx.x >> 6);
  const int b = row >> 8, t = row & 255;
  if (t >= sl[b]) return;            // dead token (per-wave uniform exit)
  const int orow = boff[b] + t;
  const int lane = threadIdx.x & 63;
  const int ci = ch[row], wi = wd[row], pi = ps[row];
  float v[8];
#pragma unroll
  for (int j = 0; j < 2; ++j) {
    const int d = j * 256 + lane * 4;
    float4 f;
    if (d < 128)      f = *(const float4*)&ctab[(size_t)ci * 128 + d];
    else if (d < 428) f = *(const float4*)&wtab[(size_t)wi * 300 + (d - 128)];
    else if (d < 492) f = *(const float4*)&ptab[(size_t)pi * 64 + (d - 428)];
    else              f = *(const float4*)&spo[(size_t)b * 20 + (d - 492)];
    v[j * 4 + 0] = f.x; v[j * 4 + 1] = f.y; v[j * 4 + 2] = f.z; v[j * 4 + 3] = f.w;
  }
  float s = 0.f;
#pragma unroll
  for (int i = 0; i < 8; ++i) s += v[i];
  const float mean = wredsum(s) * (1.0f / 512.0f);
  float vs = 0.f;
#pragma unroll
  for (int i = 0; i < 8; ++i) { const float d = v[i] - mean; vs += d * d; }
  const float rstd = rsqrtf(wredsum(vs) * (1.0f / 512.0f) + 1e-5f);
#pragma unroll
  for (int j = 0; j < 2; ++j) {
    const int d = j * 256 + lane * 4;
    const float4 gv = *(const float4*)&g[d];
    const float4 bv = *(const float4*)&be[d];
    short4_ ob;
    ob[0] = (short)f2b((v[j * 4 + 0] - mean) * rstd * gv.x + bv.x);
    ob[1] = (short)f2b((v[j * 4 + 1] - mean) * rstd * gv.y + bv.y);
    ob[2] = (short)f2b((v[j * 4 + 2] - mean) * rstd * gv.z + bv.z);
    ob[3] = (short)f2b((v[j * 4 + 3] - mean) * rstd * gv.w + bv.w);
    *(short4_*)&xc[(size_t)orow * DD + d] = ob;
  }
}

// ---------------- MFMA GEMM, TMx128, 2-buffer issue-ahead, XCD interleave ---
// TM=64 everywhere: LDS 48KB -> 3 blocks/CU; cross-block overlap hides the
// per-K-step vmcnt drain (R12/R13 wins; TN=64 overshoots - R14).
// Live-aware swizzle: XCD d%8 owns m-panels == d%8 (mod 8), walks all n of
// one panel -> A-panel stays L2-resident. Bijective (nwg%8==0).
// EPI: 1 bf16+bias+relu; 5 fused QKV scatter via rowmap; 7 bf16+bias+bf16 res
template <int EPI, int TM>
__global__ __launch_bounds__(256) void gemm_mfma(
    const unsigned short* __restrict__ A, const unsigned short* __restrict__ Bt,
    const float* __restrict__ bias, const float* __restrict__ bias2,
    const float* __restrict__ bias3, const unsigned short* __restrict__ res,
    const int* __restrict__ Mptr, const int* __restrict__ rowmap,
    void* __restrict__ outv, void* __restrict__ out2v, void* __restrict__ out3v,
    int M, int N, int K) {
  constexpr int MI = TM / 32;          // acc rows per wave (2 or 4)
  const int Mp = Mptr[0];
  const int nx = gridDim.x;
  const int flat = blockIdx.y * nx + blockIdx.x;
  const int mlo = flat & 7, rr_ = flat >> 3;
  const int bx = rr_ % nx, by = (rr_ / nx) * 8 + mlo;
  const int m0 = by * TM, n0 = bx * 128;
  if (m0 >= Mp) return;  // block-uniform exit (whole tile dead)
  __shared__ unsigned short As[2][TM * 64];
  __shared__ unsigned short Bs[2][128 * 64];
  const int tid = threadIdx.x;
  const int wid = tid >> 6, lane = tid & 63;
  const int wr = wid >> 1, wc = wid & 1;
  const int cl = lane & 15, rg = lane >> 4;
  f32x4 acc[MI][4];
#pragma unroll
  for (int i = 0; i < MI; ++i)
#pragma unroll
    for (int j = 0; j < 4; ++j) acc[i][j] = (f32x4){0.f, 0.f, 0.f, 0.f};

  const int rbase = tid >> 3, sl = tid & 7;
  const int sc = 8 * (sl ^ (rbase & 7));  // pre-swizzled source column (elems)

  auto stage = [&](int buf, int k0) {
#pragma unroll
    for (int i = 0; i < TM / 32; ++i) {
      const int r = i * 32 + rbase;
      gl_lds16(A + (size_t)(m0 + r) * K + k0 + sc,
               (char*)As[buf] + (i * 256 + tid) * 16);
    }
#pragma unroll
    for (int i = 0; i < 4; ++i) {
      const int r = i * 32 + rbase;
      gl_lds16(Bt + (size_t)(n0 + r) * K + k0 + sc,
               (char*)Bs[buf] + (i * 256 + tid) * 16);
    }
  };

  stage(0, 0);
  __syncthreads();  // implicit vmcnt(0) drain: buf0 staged
  int cur = 0;
  for (int k0 = 0; k0 < K; k0 += 64) {
    if (k0 + 64 < K) stage(cur ^ 1, k0 + 64);  // issue-ahead: latency under MFMA
#pragma unroll
    for (int ks = 0; ks < 2; ++ks) {
      short8 a[MI], b[4];
      const int kbyte = ks * 64 + rg * 16;
#pragma unroll
      for (int f = 0; f < MI; ++f) {
        const int am = wr * (TM / 2) + f * 16 + cl;
        a[f] = *(const short8*)((const char*)As[cur] + am * 128 +
                                (kbyte ^ ((am & 7) << 4)));
      }
#pragma unroll
      for (int f = 0; f < 4; ++f) {
        const int bn = wc * 64 + f * 16 + cl;
        b[f] = *(const short8*)((const char*)Bs[cur] + bn * 128 +
                                (kbyte ^ ((bn & 7) << 4)));
      }
#pragma unroll
      for (int mi = 0; mi < MI; ++mi)
#pragma unroll
        for (int ni = 0; ni < 4; ++ni)
          acc[mi][ni] = __builtin_amdgcn_mfma_f32_16x16x32_bf16(a[mi], b[ni],
                                                                acc[mi][ni], 0, 0, 0);
    }
    __syncthreads();  // drains this iter's stage; frees buf[cur]
    cur ^= 1;
  }

  int rm[MI][4];
  if constexpr (EPI == 5) {
#pragma unroll
    for (int mi = 0; mi < MI; ++mi) {
      const int mb_ = m0 + wr * (TM / 2) + mi * 16 + rg * 4;
#pragma unroll
      for (int i = 0; i < 4; ++i)
        rm[mi][i] = (mb_ + i < Mp) ? rowmap[mb_ + i] : -1;
    }
  }

#pragma unroll
  for (int ni = 0; ni < 4; ++ni) {
    const int n = n0 + wc * 64 + ni * 16 + cl;
    float bv;
    if constexpr (EPI == 5) {
      bv = (n < 512) ? bias[n] : (n < 1024 ? bias2[n - 512] : bias3[n - 1024]);
    } else {
      bv = bias[n];
    }
#pragma unroll
    for (int mi = 0; mi < MI; ++mi) {
      if constexpr (EPI == 5) {
        const int hh = (n >> 6) & 7, d = n & 63;
        if (n < 1024) {        // q or k scatter [B,H,T,DH] bf16
          unsigned short* outp = (unsigned short*)((n < 512) ? outv : out2v);
#pragma unroll
          for (int i = 0; i < 4; ++i) {
            const int rmv = rm[mi][i];
            if (rmv >= 0) {
              const int bb = rmv >> 8, tt = rmv & 255;
              outp[(((size_t)(bb * HH + hh) * TT + tt) << 6) + d] =
                  f2b(acc[mi][ni][i] + bv);
            }
          }
        } else {               // v scatter [B,H,DH,T] f16
          const int rm0 = rm[mi][0];
          if (rm0 >= 0 && rm[mi][3] == rm0 + 3) {   // contiguous, same b
            half4 pk;
#pragma unroll
            for (int i = 0; i < 4; ++i) pk[i] = (_Float16)(acc[mi][ni][i] + bv);
            *(half4*)((_Float16*)out3v +
                      ((((size_t)((rm0 >> 8) * HH + hh) * DH + d) << 8) + (rm0 & 255))) = pk;
          } else {
#pragma unroll
            for (int i = 0; i < 4; ++i) {
              const int rmv = rm[mi][i];
              if (rmv >= 0)
                ((_Float16*)out3v)[(((size_t)((rmv >> 8) * HH + hh) * DH + d) << 8) +
                                   (rmv & 255)] = (_Float16)(acc[mi][ni][i] + bv);
            }
          }
        }
      } else {
#pragma unroll
        for (int i = 0; i < 4; ++i) {
          const int m = m0 + wr * (TM / 2) + mi * 16 + rg * 4 + i;
          const float v = acc[mi][ni][i] + bv;
          if constexpr (EPI == 1) {
            ((unsigned short*)outv)[(size_t)m * N + n] = f2b(fmaxf(v, 0.f));
          } else if constexpr (EPI == 7) {
            ((unsigned short*)outv)[(size_t)m * N + n] =
                f2b(v + b2f(res[(size_t)m * N + n]));
          }
        }
      }
    }
  }
}

// ---------------- MFMA flash attention, one block per (b,h,q-tile) ----------
__global__ __launch_bounds__(256) void attn_mfma_k(
    const unsigned short* __restrict__ qb, const unsigned short* __restrict__ kbp,
    const _Float16* __restrict__ vtp, const int* __restrict__ seq_len,
    const int* __restrict__ boff, unsigned short* __restrict__ cb) {
  __shared__ unsigned short Ks[256 * 64];  // [t][d] bf16, 16B-slot XOR swizzle
  __shared__ _Float16 Vs[64 * 256];        // [d][t] f16, swizzled
  __shared__ unsigned short Os[64 * 64];   // out transpose stage, swizzled
  const int bh = blockIdx.x >> 2;
  const int qt4 = blockIdx.x & 3;
  const int b = bh >> 3, h = bh & 7;
  const int len = seq_len[b];
  if (qt4 * 64 >= len) return;  // block-uniform early exit
  const int tid = threadIdx.x;
  const int wid = tid >> 6, lane = tid & 63;
  const int cl = lane & 15, rg = lane >> 4;
  const int off = boff[b];

  {  // stage K (len-bounded) and V^T (skip dead 64-col groups)
    const int r = tid >> 3, sl = tid & 7;
#pragma unroll
    for (int i = 0; i < 8; ++i) {
      if (i * 32 < len) {
        const int row = i * 32 + r;
        gl_lds16(kbp + ((size_t)bh * TT + row) * DH + 8 * (sl ^ (row & 7)),
                 (char*)Ks + (i * 256 + tid) * 16);
      }
    }
#pragma unroll
    for (int i = 0; i < 8; ++i) {
      const int u = i * 256 + tid;
      const int vrow = u >> 5, vsl = u & 31;
      if (64 * (vsl >> 3) < len)
        gl_lds16(vtp + ((size_t)bh * DH + vrow) * TT + 8 * (vsl ^ (vrow & 7)),
                 (char*)Vs + u * 16);
    }
  }
  __syncthreads();

  f32x4 o[4];
#pragma unroll
  for (int db = 0; db < 4; ++db) o[db] = (f32x4){0.f, 0.f, 0.f, 0.f};
  {
    const int q0 = qt4 * 64 + wid * 16;
    short8 bqf[2];
    const unsigned short* qp = qb + ((size_t)bh * TT + q0 + cl) * DH + rg * 8;
    bqf[0] = *(const short8*)qp;
    bqf[1] = *(const short8*)(qp + 32);
    f32x4 s[16];
#pragma unroll
    for (int kk = 0; kk < 16; ++kk) {
      s[kk] = (f32x4){0.f, 0.f, 0.f, 0.f};
      if (kk * 16 < len) {
        const int row = kk * 16 + cl;
        const char* base = (const char*)Ks + row * 128;
        const int sw = (row & 7) << 4;
        const short8 a0 = *(const short8*)(base + ((rg * 16) ^ sw));
        const short8 a1 = *(const short8*)(base + ((64 + rg * 16) ^ sw));
        s[kk] = __builtin_amdgcn_mfma_f32_16x16x32_bf16(a0, bqf[0], s[kk], 0, 0, 0);
        s[kk] = __builtin_amdgcn_mfma_f32_16x16x32_bf16(a1, bqf[1], s[kk], 0, 0, 0);
      }
    }
    float mx = -3.0e38f;
#pragma unroll
    for (int kk = 0; kk < 16; ++kk)
      if (kk * 16 < len) {
#pragma unroll
        for (int i = 0; i < 4; ++i) {
          float v = s[kk][i] * 0.125f;
          v = (kk * 16 + rg * 4 + i < len) ? v : -3.0e38f;
          s[kk][i] = v;
          mx = fmaxf(mx, v);
        }
      }
    mx = fmaxf(mx, __shfl_xor(mx, 16, 64));
    mx = fmaxf(mx, __shfl_xor(mx, 32, 64));
    float lsum = 0.f;
#pragma unroll
    for (int kk = 0; kk < 16; ++kk)
      if (kk * 16 < len) {
#pragma unroll
        for (int i = 0; i < 4; ++i) {
          const float p = __expf(s[kk][i] - mx);
          s[kk][i] = p;
          lsum += p;
        }
      }
    lsum += __shfl_xor(lsum, 16, 64);
    lsum += __shfl_xor(lsum, 32, 64);
    const float rl = 1.0f / lsum;
#pragma unroll
    for (int kk = 0; kk < 16; ++kk)
      if (kk * 16 < len) {
        half4 bp;
#pragma unroll
        for (int i = 0; i < 4; ++i) bp[i] = (_Float16)(s[kk][i] * rl);
#pragma unroll
        for (int db = 0; db < 4; ++db) {
          const int vrow = db * 16 + cl;
          const int byte = kk * 32 + rg * 8;
          const half4 a = *(const half4*)((const char*)Vs + vrow * 512 +
                            ((byte & ~15) ^ ((vrow & 7) << 4)) + (byte & 15));
          o[db] = __builtin_amdgcn_mfma_f32_16x16x16f16(a, bp, o[db], 0, 0, 0);
        }
      }
  }
  {  // write ctx^T frags into Os (no barrier needed: Os untouched so far)
    const int orow = wid * 16 + cl;
    char* obase = (char*)Os + orow * 128;
    const int sw = (orow & 7) << 4;
#pragma unroll
    for (int db = 0; db < 4; ++db) {
      short4_ pk;
#pragma unroll
      for (int i = 0; i < 4; ++i) pk[i] = (short)f2b(o[db][i]);
      const int byte = db * 32 + rg * 8;
      *(short4_*)(obase + ((byte & ~15) ^ sw) + (byte & 15)) = pk;
    }
  }
  __syncthreads();
  {  // coalesced copy Os (64q x 64d bf16) -> compacted cb, rows t < len only
    const int r = tid >> 2, part = tid & 3;
    const int t = qt4 * 64 + r;
    if (t < len) {
      const int sw = (r & 7) << 4;
      const char* rbase = (const char*)Os + r * 128;
      const short8 w0 = *(const short8*)(rbase + ((part * 32) ^ sw));
      const short8 w1 = *(const short8*)(rbase + ((part * 32 + 16) ^ sw));
      unsigned short* dst = cb + ((size_t)(off + t)) * DD + h * DH + part * 16;
      *(short8*)dst = w0;
      *(short8*)(dst + 8) = w1;
    }
  }
}

// ---------------- row LayerNorm (compacted, 4 rows / block) -----------------
__global__ __launch_bounds__(256) void ln_k(const unsigned short* __restrict__ a,
                                            const float* __restrict__ g,
                                            const float* __restrict__ be,
                                            const int* __restrict__ Mptr,
                                            unsigned short* __restrict__ outb) {
  const int row = blockIdx.x * 4 + (threadIdx.x >> 6);
  if (row >= Mptr[0]) return;  // per-wave uniform exit (no barriers below)
  const int lane = threadIdx.x & 63;
  float v[8];
  {
    const short8 va = *(const short8*)&a[(size_t)row * DD + lane * 8];
#pragma unroll
    for (int i = 0; i < 8; ++i) v[i] = b2f((unsigned short)va[i]);
  }
  float s = 0.f;
#pragma unroll
  for (int i = 0; i < 8; ++i) s += v[i];
  const float mean = wredsum(s) * (1.0f / 512.0f);
  float vs = 0.f;
#pragma unroll
  for (int i = 0; i < 8; ++i) { const float d = v[i] - mean; vs += d * d; }
  const float rstd = rsqrtf(wredsum(vs) * (1.0f / 512.0f) + 1e-5f);
  const float4 g0 = *(const float4*)&g[lane * 8];
  const float4 g1 = *(const float4*)&g[lane * 8 + 4];
  const float4 b0 = *(const float4*)&be[lane * 8];
  const float4 b1 = *(const float4*)&be[lane * 8 + 4];
  const float gg[8] = {g0.x, g0.y, g0.z, g0.w, g1.x, g1.y, g1.z, g1.w};
  const float bb[8] = {b0.x, b0.y, b0.z, b0.w, b1.x, b1.y, b1.z, b1.w};
  short8 ob;
#pragma unroll
  for (int i = 0; i < 8; ++i)
    ob[i] = (short)f2b((v[i] - mean) * rstd * gg[i] + bb[i]);
  *(short8*)&outb[(size_t)row * DD + lane * 8] = ob;
}

// ---------------- logits = xc(bf16) @ Wout + bout,  N=25 --------------------
__global__ __launch_bounds__(256) void logits_k(const unsigned short* __restrict__ xb,
                                                const float* __restrict__ W,
                                                const float* __restrict__ bo,
                                                const int* __restrict__ Mptr,
                                                float* __restrict__ lg) {
  const int r0 = blockIdx.x * 8;
  if (r0 >= Mptr[0]) return;
  __shared__ float xs[8][516];
  for (int i = threadIdx.x; i < 512; i += 256) {
    const int rr = i >> 6, c8 = (i & 63) * 8;
    const short8 v = *(const short8*)&xb[(size_t)(r0 + rr) * DD + c8];
#pragma unroll
    for (int j = 0; j < 8; ++j) xs[rr][c8 + j] = b2f((unsigned short)v[j]);
  }
  __syncthreads();
  const int r = threadIdx.x >> 5, c = threadIdx.x & 31;
  if (c < CC) {
    float acc = 0.f;
#pragma unroll 8
    for (int k = 0; k < DD; ++k) acc += xs[r][k] * W[k * CC + c];
    lg[(size_t)(r0 + r) * CC + c] = acc + bo[c];
  }
}

// ---------------- CRF: linear-domain scan via v_readlane (compacted) --------
__global__ __launch_bounds__(64) void crf_k(const float* __restrict__ lg,
                                            const int* __restrict__ tag,
                                            const int* __restrict__ seq_len,
                                            const int* __restrict__ boff,
                                            const float* __restrict__ trans,
                                            float* __restrict__ nll) {
  __shared__ float eexp[TT * CC + 64];
  __shared__ float tr[CC * CC];
  const int b = blockIdx.x;
  const int l = threadIdx.x;
  const int len = seq_len[b];
  const float* lgb = lg + (size_t)boff[b] * CC;
  for (int i = l; i < len * CC; i += 64) eexp[i] = __expf(lgb[i]);
  for (int i = l; i < CC * CC; i += 64) tr[i] = trans[i];
  __syncthreads();
  const int lc = (l < CC) ? l : (CC - 1);
  float et[CC];
#pragma unroll
  for (int i = 0; i < CC; ++i) et[i] = __expf(tr[i * CC + lc]);
  const float e00 = lgb[0];
  float M = e00;
  float A = (l < CC) ? __expf(lgb[l] - e00) : 0.f;
  for (int t = 1; t < len; ++t) {
    const float e = eexp[t * CC + lc];
    float s0 = 0.f, s1 = 0.f, s2 = 0.f, s3 = 0.f, s4 = 0.f;
#pragma unroll
    for (int i = 0; i < CC; i += 5) {
      s0 += rdlane(A, i + 0) * et[i + 0];
      s1 += rdlane(A, i + 1) * et[i + 1];
      s2 += rdlane(A, i + 2) * et[i + 2];
      s3 += rdlane(A, i + 3) * et[i + 3];
      s4 += rdlane(A, i + 4) * et[i + 4];
    }
    A = (((s0 + s1) + (s2 + s3)) + s4) * e;
    if ((t & 3) == 0) {
      const float r = rdlane(A, 0);  // A_0 > 0 always (dense transitions)
      M += __logf(r);
      A *= __builtin_amdgcn_rcpf(r);
    }
  }
  const float tot = wredsum((l < CC) ? A : 0.f);
  float gold = 0.f;
  for (int t = l; t < len; t += 64)
    gold += lgb[t * CC + tag[b * TT + t]];
  for (int t = 1 + l; t < len; t += 64)
    gold += tr[tag[b * TT + t - 1] * CC + tag[b * TT + t]];
  gold = wredsum(gold);
  if (l == 0) nll[b] = (M + __logf(tot)) - gold;
}

__global__ __launch_bounds__(64) void final_k(const float* __restrict__ nll,
                                              float* __restrict__ out) {
  float v = nll[threadIdx.x];
  v = wredsum(v);
  if (threadIdx.x == 0) out[0] = v * (1.0f / 64.0f);
}

}  // namespace

extern "C" void kernel_launch(void* const* d_in, const int* in_sizes, int n_in,
                              void* d_out, int out_size, void* d_ws, size_t ws_size,
                              hipStream_t stream) {
  (void)in_sizes; (void)n_in; (void)out_size; (void)ws_size;
  const int* chi = (const int*)d_in[0];
  const int* wdi = (const int*)d_in[1];
  const int* psi = (const int*)d_in[2];
  const float* spo = (const float*)d_in[3];
  const int* seq_len = (const int*)d_in[4];
  const int* tag = (const int*)d_in[5];
  const float* ctab = (const float*)d_in[6];
  const float* wtab = (const float*)d_in[7];
  const float* ptab = (const float*)d_in[8];
  const float* ln0g = (const float*)d_in[9];
  const float* ln0b = (const float*)d_in[10];
  const float* Wq = (const float*)d_in[11];
  const float* bq = (const float*)d_in[12];
  const float* Wk = (const float*)d_in[13];
  const float* bk = (const float*)d_in[14];
  const float* Wv = (const float*)d_in[15];
  const float* bv = (const float*)d_in[16];
  const float* Wo = (const float*)d_in[17];
  const float* bo = (const float*)d_in[18];
  const float* ln1g = (const float*)d_in[19];
  const float* ln1b = (const float*)d_in[20];
  const float* W1 = (const float*)d_in[21];
  const float* b1 = (const float*)d_in[22];
  const float* W2 = (const float*)d_in[23];
  const float* b2 = (const float*)d_in[24];
  const float* ln2g = (const float*)d_in[25];
  const float* ln2b = (const float*)d_in[26];
  const float* Wout = (const float*)d_in[27];
  const float* bout = (const float*)d_in[28];
  const float* trans = (const float*)d_in[29];

  // ---- workspace layout (~221 MB), all buffers disjoint ----
  char* w8 = (char*)d_ws;
  unsigned short* ib  = (unsigned short*)(w8);             // 64MB ffn inner [16384][2048]
  unsigned short* xc  = (unsigned short*)(w8 + 64 * MB);   // 16MB x compact bf16
  unsigned short* cbx = (unsigned short*)(w8 + 80 * MB);   // 16MB ctx compact bf16
  unsigned short* ab  = (unsigned short*)(w8 + 96 * MB);   // 16MB att_out+x bf16
  unsigned short* hb  = (unsigned short*)(w8 + 112 * MB);  // 16MB h1 bf16
  unsigned short* t0b = (unsigned short*)(w8 + 128 * MB);  // 16MB ffn_out+h1 bf16
  unsigned short* qbuf = (unsigned short*)(w8 + 144 * MB); // 16MB q bf16 [B,H,T,DH]
  unsigned short* kbuf = (unsigned short*)(w8 + 160 * MB); // 16MB k bf16 [B,H,T,DH]
  _Float16* vtb = (_Float16*)(w8 + 176 * MB);              // 16MB v^T f16 [B,H,DH,T]
  unsigned short* wqkv = (unsigned short*)(w8 + 192 * MB); // [L][1536][512] 6MB
  unsigned short* wot = (unsigned short*)(w8 + 198 * MB);  // [L][512][512] 2MB
  unsigned short* w1t = (unsigned short*)(w8 + 200 * MB);  // [L][2048][512] 8MB
  unsigned short* w2t = (unsigned short*)(w8 + 208 * MB);  // [L][512][2048] 8MB
  float* lg = (float*)(w8 + 216 * MB);                     // 16384*25 f32
  float* nll = (float*)(w8 + 218 * MB);
  int* boff = (int*)(w8 + 219 * MB);                       // [65]; boff[64] = M'
  int* rowmap = (int*)(w8 + 220 * MB);                     // [16384] (b<<8)|t
  const int* Mptr = boff + 64;

  rowmap_k<<<BB, 256, 0, stream>>>(seq_len, boff, rowmap);

  const size_t QKVS = (size_t)1536 * 512;
  wconv_k<3><<<dim3(8, 8, 3 * LT), 256, 0, stream>>>(
      Wq, Wk, Wv, wqkv, DD, DD, QKVS, (size_t)512 * 512);
  wconv_k<1><<<dim3(8, 8, LT), 256, 0, stream>>>(
      Wo, nullptr, nullptr, wot, DD, DD, (size_t)DD * DD, 0);
  wconv_k<1><<<dim3(8, 32, LT), 256, 0, stream>>>(
      W1, nullptr, nullptr, w1t, DD, FF, (size_t)DD * FF, 0);
  wconv_k<1><<<dim3(32, 8, LT), 256, 0, stream>>>(
      W2, nullptr, nullptr, w2t, FF, DD, (size_t)FF * DD, 0);

  embed_ln0_k<<<M_ALL / 4, 256, 0, stream>>>(chi, wdi, psi, spo, ctab, wtab, ptab,
                                             ln0g, ln0b, seq_len, boff, xc);

  for (int l = 0; l < LT; ++l) {
    gemm_mfma<5, 64><<<dim3(12, 256), 256, 0, stream>>>(
        xc, wqkv + (size_t)l * QKVS, bq + l * DD, bk + l * DD, bv + l * DD,
        nullptr, Mptr, rowmap, qbuf, kbuf, vtb, M_ALL, 1536, DD);
    attn_mfma_k<<<BB * HH * 4, 256, 0, stream>>>(qbuf, kbuf, vtb, seq_len, boff, cbx);
    gemm_mfma<7, 64><<<dim3(4, 256), 256, 0, stream>>>(
        cbx, wot + (size_t)l * DD * DD, bo + l * DD, nullptr, nullptr,
        xc, Mptr, nullptr, ab, nullptr, nullptr, M_ALL, DD, DD);
    ln_k<<<M_ALL / 4, 256, 0, stream>>>(ab, ln1g + l * DD, ln1b + l * DD, Mptr, hb);
    gemm_mfma<1, 64><<<dim3(FF / 128, 256), 256, 0, stream>>>(
        hb, w1t + (size_t)l * FF * DD, b1 + l * FF, nullptr, nullptr,
        nullptr, Mptr, nullptr, ib, nullptr, nullptr, M_ALL, FF, DD);
    gemm_mfma<7, 64><<<dim3(4, 256), 256, 0, stream>>>(
        ib, w2t + (size_t)l * FF * DD, b2 + l * DD, nullptr, nullptr,
        hb, Mptr, nullptr, t0b, nullptr, nullptr, M_ALL, DD, FF);
    ln_k<<<M_ALL / 4, 256, 0, stream>>>(t0b, ln2g + l * DD, ln2b + l * DD, Mptr, xc);
  }
  logits_k<<<M_ALL / 8, 256, 0, stream>>>(xc, Wout, bout, Mptr, lg);
  crf_k<<<BB, 64, 0, stream>>>(lg, tag, seq_len, boff, trans, nll);
  final_k<<<1, 64, 0, stream>>>(nll, (float*)d_out);
}